// Round 6
// baseline (3068.454 us; speedup 1.0000x reference)
//
#include <hip/hip_runtime.h>
#include <stdint.h>

#define BB 8
#define NN 2048
#define DD 64
#define REGv 0.1f
#define NUM_ITERS 50
#define EPS_NORM 1e-8f
#define EPS_SINK 1e-10f
#define GRID_P 256u
#define NBAR 128

typedef float f4 __attribute__((ext_vector_type(4)));
#define KEEP(x) asm volatile("" : "+v"(x))

__device__ __forceinline__ float dotf4(f4 a, f4 b) {
    return a.x * b.x + a.y * b.y + a.z * b.z + a.w * b.w;
}

// ---------------- init: maxd2 = 0, barrier counters = 0 ----------------
__global__ void init_k(unsigned* maxd, unsigned* bar) {
    int t = threadIdx.x;
    if (t < BB) maxd[t] = 0u;
    if (t < NBAR) bar[t] = 0u;
}

// ---------------- row squared norms (one wave per row) ----------------
__global__ void sq_k(const float* __restrict__ x0, const float* __restrict__ x1,
                     float* __restrict__ sq0, float* __restrict__ sq1) {
    int w = (blockIdx.x * 256 + threadIdx.x) >> 6;
    int lane = threadIdx.x & 63;
    if (w >= 2 * BB * NN) return;
    const float* src = (w < BB * NN) ? x0 : x1;
    int r = (w < BB * NN) ? w : w - BB * NN;
    float val = src[(size_t)r * DD + lane];
    float s = val * val;
    #pragma unroll
    for (int off = 32; off; off >>= 1) s += __shfl_xor(s, off);
    if (lane == 0) ((w < BB * NN) ? sq0 : sq1)[r] = s;
}

// ---------------- fused cdist: WRITE=0 -> max(d2); WRITE=1 -> K=exp ----------------
template<int WRITE>
__global__ __launch_bounds__(256) void distc_k(const float* __restrict__ x0,
                                               const float* __restrict__ x1,
                                               const float* __restrict__ sq0,
                                               const float* __restrict__ sq1,
                                               float* __restrict__ Kd,
                                               unsigned* __restrict__ maxd) {
    __shared__ float x0s[128 * 68];
    __shared__ float x1t[64 * 68];
    __shared__ float wred[4];
    int bid = blockIdx.x;
    int b = bid >> 9;
    int tile = bid & 511;
    int ti = tile >> 5, tj = tile & 31;
    int i0 = ti * 128, j0 = tj * 64;
    int t = threadIdx.x;

    const float4* g0 = (const float4*)(x0 + ((size_t)b * NN + i0) * DD);
    #pragma unroll
    for (int rep = 0; rep < 8; rep++) {
        int e = rep * 256 + t;
        int row = e >> 4, c4 = e & 15;
        *(float4*)&x0s[row * 68 + c4 * 4] = g0[row * 16 + c4];
    }
    const float4* g1 = (const float4*)(x1 + ((size_t)b * NN + j0) * DD);
    #pragma unroll
    for (int rep = 0; rep < 4; rep++) {
        int e = rep * 256 + t;
        int row = e >> 4, c4 = e & 15;
        float4 a = g1[row * 16 + c4];
        x1t[(c4 * 4 + 0) * 68 + row] = a.x;
        x1t[(c4 * 4 + 1) * 68 + row] = a.y;
        x1t[(c4 * 4 + 2) * 68 + row] = a.z;
        x1t[(c4 * 4 + 3) * 68 + row] = a.w;
    }
    __syncthreads();

    int tx = t & 15, ty = t >> 4;
    float4 acc4[8];
    #pragma unroll
    for (int di = 0; di < 8; di++) acc4[di] = make_float4(0.f, 0.f, 0.f, 0.f);

    #pragma unroll
    for (int k4 = 0; k4 < 16; k4++) {
        float4 b0 = *(const float4*)&x1t[(k4 * 4 + 0) * 68 + tx * 4];
        float4 b1 = *(const float4*)&x1t[(k4 * 4 + 1) * 68 + tx * 4];
        float4 b2 = *(const float4*)&x1t[(k4 * 4 + 2) * 68 + tx * 4];
        float4 b3 = *(const float4*)&x1t[(k4 * 4 + 3) * 68 + tx * 4];
        #pragma unroll
        for (int di = 0; di < 8; di++) {
            float4 a = *(const float4*)&x0s[(ty * 8 + di) * 68 + k4 * 4];
            acc4[di].x += a.x * b0.x + a.y * b1.x + a.z * b2.x + a.w * b3.x;
            acc4[di].y += a.x * b0.y + a.y * b1.y + a.z * b2.y + a.w * b3.y;
            acc4[di].z += a.x * b0.z + a.y * b1.z + a.z * b2.z + a.w * b3.z;
            acc4[di].w += a.x * b0.w + a.y * b1.w + a.z * b2.w + a.w * b3.w;
        }
    }

    int ib = b * NN + i0 + ty * 8;
    float4 s1 = *(const float4*)&sq1[b * NN + j0 + tx * 4];

    if (WRITE) {
        float mv = sqrtf(__uint_as_float(maxd[b])) + EPS_NORM;
        #pragma unroll
        for (int di = 0; di < 8; di++) {
            float s0 = sq0[ib + di];
            float4 o;
            o.x = expf(-((sqrtf(fmaxf(s0 + s1.x - 2.f * acc4[di].x, 0.f)) / mv) / REGv));
            o.y = expf(-((sqrtf(fmaxf(s0 + s1.y - 2.f * acc4[di].y, 0.f)) / mv) / REGv));
            o.z = expf(-((sqrtf(fmaxf(s0 + s1.z - 2.f * acc4[di].z, 0.f)) / mv) / REGv));
            o.w = expf(-((sqrtf(fmaxf(s0 + s1.w - 2.f * acc4[di].w, 0.f)) / mv) / REGv));
            *(float4*)&Kd[(size_t)(ib + di) * NN + j0 + tx * 4] = o;
        }
    } else {
        float lm = 0.0f;
        #pragma unroll
        for (int di = 0; di < 8; di++) {
            float s0 = sq0[ib + di];
            lm = fmaxf(lm, fmaxf(s0 + s1.x - 2.f * acc4[di].x, 0.f));
            lm = fmaxf(lm, fmaxf(s0 + s1.y - 2.f * acc4[di].y, 0.f));
            lm = fmaxf(lm, fmaxf(s0 + s1.z - 2.f * acc4[di].z, 0.f));
            lm = fmaxf(lm, fmaxf(s0 + s1.w - 2.f * acc4[di].w, 0.f));
        }
        #pragma unroll
        for (int off = 32; off; off >>= 1) lm = fmaxf(lm, __shfl_xor(lm, off));
        if ((t & 63) == 0) wred[t >> 6] = lm;
        __syncthreads();
        if (t == 0) {
            float m = fmaxf(fmaxf(wred[0], wred[1]), fmaxf(wred[2], wred[3]));
            atomicMax(&maxd[b], __float_as_uint(m));  // d2 >= 0: uint cmp == float cmp
        }
    }
}

// ---------------- hand-rolled grid barrier (256 co-resident blocks) ----------------
__device__ __forceinline__ void gbar(unsigned* c, int t) {
    __syncthreads();   // drain block stores before arrive
    if (t == 0) {
        __threadfence();                 // release (agent scope)
        atomicAdd(c, 1u);
        while (__hip_atomic_load(c, __ATOMIC_RELAXED, __HIP_MEMORY_SCOPE_AGENT) < GRID_P)
            __builtin_amdgcn_s_sleep(1);
        __threadfence();                 // acquire
    }
    __syncthreads();
}

// ---------------- persistent Sinkhorn ----------------
// 256 blocks x 1024 threads (16 waves), 1 block/CU (LDS 152 KB), hard 128-VGPR cap.
// Block q: batch b=q>>5, rows G0=g*64 .. G0+63. Wave w owns rows G0+4w..G0+4w+3:
// rows 0-2 in 24 f4 regs (96 VGPR), row 3 in LDS (16 rows = 128 KB).
// Latin-square column rotation: wave w's reg slot k holds physical f4-col
// ((w&7)+k)&7)*64 + l, so sigma-merge step s has all 16 waves RMW disjoint
// LDS chunks with STATIC register indices (no dynamic Kreg indexing).
__global__ __launch_bounds__(1024)
void persist_k(const float* __restrict__ Kd,
               float* __restrict__ partial,
               float* __restrict__ vglob,
               unsigned* __restrict__ bar,
               int* __restrict__ out) {
    __shared__ f4 Kl4[16 * 512];   // 128 KB: one LDS K-row per wave
    __shared__ f4 vbuf4[512];      // 8 KB
    __shared__ f4 s0buf[512];      // 8 KB: sigma waves 0-7 / vred scratch
    __shared__ f4 s1buf[512];      // 8 KB: sigma waves 8-15

    const int t = threadIdx.x;
    const int l = t & 63;
    const int w = t >> 6;
    const int p = w & 7;
    const int q = blockIdx.x;
    const int b = q >> 5;
    const int g = q & 31;

    const f4* Kg = (const f4*)Kd + (size_t)(b * NN + g * 64 + w * 4) * 512;
    const int ldsrow = w * 512;

    // stage: rotated columns. slot k <-> physical f4-col idx = ((p+k)&7)*64 + l
    f4 Kreg[3][8];
    #pragma unroll
    for (int k = 0; k < 8; k++) {
        int idx = (((p + k) & 7) << 6) + l;
        Kl4[ldsrow + idx] = Kg[3 * 512 + idx];
        Kreg[0][k] = Kg[0 * 512 + idx];
        Kreg[1][k] = Kg[1 * 512 + idx];
        Kreg[2][k] = Kg[2 * 512 + idx];
        KEEP(Kreg[0][k]); KEEP(Kreg[1][k]); KEEP(Kreg[2][k]);
    }

    if (t < 512) vbuf4[t] = (f4){1.0f / NN, 1.0f / NN, 1.0f / NN, 1.0f / NN};

    float u[4];

    for (int it = 0; it < NUM_ITERS; ++it) {
        __syncthreads();   // vbuf (and initial staging) visible

        // ---- phase A: row dots -> u (wave-local, xor-reduce) ----
        float dp0 = 0.f, dp1 = 0.f, dp2 = 0.f, dp3 = 0.f;
        #pragma unroll
        for (int k = 0; k < 8; k++) {
            int idx = (((p + k) & 7) << 6) + l;
            f4 vk = vbuf4[idx];
            dp0 += dotf4(Kreg[0][k], vk);
            dp1 += dotf4(Kreg[1][k], vk);
            dp2 += dotf4(Kreg[2][k], vk);
            dp3 += dotf4(Kl4[ldsrow + idx], vk);
        }
        float dp[4] = {dp0, dp1, dp2, dp3};
        #pragma unroll
        for (int r = 0; r < 4; r++) {
            float s = dp[r];
            #pragma unroll
            for (int off = 32; off; off >>= 1) s += __shfl_xor(s, off);
            u[r] = 1.0f / (s + EPS_SINK);
        }

        // ---- phase B: sigma into LDS, latin-square (all 16 waves, disjoint chunks) ----
        f4* mybuf = (w < 8) ? s0buf : s1buf;
        __syncthreads();   // bufs free (prev iter's readers done at loop-top sync)
        #pragma unroll
        for (int s = 0; s < 8; s++) {
            int idx = (((p + s) & 7) << 6) + l;
            f4 contrib = Kreg[0][s] * u[0] + Kreg[1][s] * u[1] + Kreg[2][s] * u[2] +
                         Kl4[ldsrow + idx] * u[3];
            if (s == 0) mybuf[idx] = contrib;
            else        mybuf[idx] = mybuf[idx] + contrib;
            __syncthreads();
        }

        // ---- write block partial (8 KB) ----
        if (t < 512)
            ((f4*)partial)[(size_t)(b * 32 + g) * 512 + t] = s0buf[t] + s1buf[t];
        gbar(&bar[2 * it], t);

        // ---- distributed v-reduce: block q -> 16 f4 of vglob ----
        {
            f4 pv;
            if (t < 512) {
                int c4 = g * 16 + (t & 15);
                int prow = t >> 4;     // 0..31
                pv = ((const f4*)partial)[(size_t)(b * 32 + prow) * 512 + c4];
                #pragma unroll
                for (int off = 16; off <= 32; off <<= 1) {
                    pv.x += __shfl_xor(pv.x, off);
                    pv.y += __shfl_xor(pv.y, off);
                    pv.z += __shfl_xor(pv.z, off);
                    pv.w += __shfl_xor(pv.w, off);
                }
                if (l < 16) s0buf[w * 16 + l] = pv;
            }
            __syncthreads();
            if (t < 16) {
                f4 s = s0buf[t];
                #pragma unroll
                for (int ww = 1; ww < 8; ww++) s += s0buf[ww * 16 + t];
                f4 vv;
                vv.x = 1.0f / (s.x + EPS_SINK);
                vv.y = 1.0f / (s.y + EPS_SINK);
                vv.z = 1.0f / (s.z + EPS_SINK);
                vv.w = 1.0f / (s.w + EPS_SINK);
                ((f4*)vglob)[q * 16 + t] = vv;
            }
        }
        gbar(&bar[2 * it + 1], t);

        // ---- reload v for this batch ----
        if (t < 512) vbuf4[t] = ((const f4*)vglob)[b * 512 + t];
    }
    __syncthreads();

    // ---- argmax of P = (u*K)*v per row (numpy first-occurrence tie-break) ----
    #pragma unroll
    for (int r = 0; r < 4; r++) {
        float best = -1.0f;
        int bi = 0x7fffffff;
        #pragma unroll
        for (int k = 0; k < 8; k++) {
            int idx = (((p + k) & 7) << 6) + l;
            f4 vk = vbuf4[idx];
            f4 kr = (r < 3) ? Kreg[r][k] : Kl4[ldsrow + idx];
            f4 pp;
            pp.x = (u[r] * kr.x) * vk.x;
            pp.y = (u[r] * kr.y) * vk.y;
            pp.z = (u[r] * kr.z) * vk.z;
            pp.w = (u[r] * kr.w) * vk.w;
            int j0 = idx * 4;   // rotated scan order -> explicit index tie-break
            if (pp.x > best || (pp.x == best && j0     < bi)) { best = pp.x; bi = j0;     }
            if (pp.y > best || (pp.y == best && j0 + 1 < bi)) { best = pp.y; bi = j0 + 1; }
            if (pp.z > best || (pp.z == best && j0 + 2 < bi)) { best = pp.z; bi = j0 + 2; }
            if (pp.w > best || (pp.w == best && j0 + 3 < bi)) { best = pp.w; bi = j0 + 3; }
        }
        #pragma unroll
        for (int off = 32; off; off >>= 1) {
            float ov = __shfl_xor(best, off);
            int oi = __shfl_xor(bi, off);
            if (ov > best || (ov == best && oi < bi)) { best = ov; bi = oi; }
        }
        if (l == 0) out[b * NN + g * 64 + w * 4 + r] = bi;
    }
}

extern "C" void kernel_launch(void* const* d_in, const int* in_sizes, int n_in,
                              void* d_out, int out_size, void* d_ws, size_t ws_size,
                              hipStream_t stream) {
    const float* x0 = (const float*)d_in[0];
    const float* x1 = (const float*)d_in[1];
    int* out = (int*)d_out;
    char* ws = (char*)d_ws;

    // ws layout (bytes)
    float* Kd      = (float*)(ws + 0ull);                 // 134217728
    float* partial = (float*)(ws + 134217728ull);         // 2097152
    float* vglob   = (float*)(ws + 136314880ull);         // 65536
    float* sq0     = (float*)(ws + 136380416ull);         // 65536
    float* sq1     = (float*)(ws + 136445952ull);         // 65536
    unsigned* maxd = (unsigned*)(ws + 136511488ull);      // 32
    unsigned* bar  = (unsigned*)(ws + 136511520ull);      // 512

    init_k<<<1, 256, 0, stream>>>(maxd, bar);
    sq_k<<<8192, 256, 0, stream>>>(x0, x1, sq0, sq1);
    distc_k<0><<<4096, 256, 0, stream>>>(x0, x1, sq0, sq1, Kd, maxd);
    distc_k<1><<<4096, 256, 0, stream>>>(x0, x1, sq0, sq1, Kd, maxd);
    persist_k<<<256, 1024, 0, stream>>>(Kd, partial, vglob, bar, out);
}